// Round 4
// baseline (2152.472 us; speedup 1.0000x reference)
//
#include <hip/hip_runtime.h>

// ============================================================================
// UnidirecLSTMLayerWithDropoutBefore: dropout(Threefry) -> x@Wi GEMM -> LSTM
// B=64, T=2048, D=256, H=256, gates (i,f,g,o), dropout 0.1, key 42.
//
// R3: k_lstm with 16 waves/WG (1024 thr, 4 waves/SIMD) for gate/MFMA overlap;
// wave owns 16 units -> no p-select; setprio around MFMA; Xp in natural
// coalesced layout [t*64+b][gate*256+u] (GEMM epilogue now 32B-contiguous);
// duplicate lanes masked off stores; c/h finals via keep-registers.
// Weights i8 VGPR-resident (validated R1/R2). MFMA floor: 64/SIMD/step.
//
// ws layout (bytes):
//   [0, 64MiB)            Xd   bf16 [131072][256]
//   [64MiB, 320MiB)       Xp   bf16 [t*64+b][1024]  (n = gate*256 + u)
//   [335544320, +512KiB)  WiT  bf16 [1024][256]
//   [336068608, +4KiB)    dq   f32 [1024]
//   [336072704, +4KiB)    qs   f32 [1024]
//   [336076800, +256KiB)  Wq   i8 packed MFMA-B frags [ntg][kt][lane][16]
// Output f32: c_last[16384] | h_last[16384] | outputs[64*2048*256]
// ============================================================================

typedef __attribute__((ext_vector_type(8))) short short8;
typedef __attribute__((ext_vector_type(4))) float floatx4;
typedef __attribute__((ext_vector_type(4))) int int4v;
typedef __attribute__((ext_vector_type(4))) unsigned short us4;

__device__ __forceinline__ unsigned short f2bf(float f) {
  unsigned int u = __float_as_uint(f);
  u = u + 0x7fffu + ((u >> 16) & 1u);   // RNE
  return (unsigned short)(u >> 16);
}
__device__ __forceinline__ float bf2f(unsigned short s) {
  return __uint_as_float(((unsigned int)s) << 16);
}
__device__ __forceinline__ float fexp2(float x) { return __builtin_amdgcn_exp2f(x); }
__device__ __forceinline__ float frcp(float x) { return __builtin_amdgcn_rcpf(x); }

// ---------------------------------------------------------------------------
// Threefry-2x32, key (0,42), partitionable scheme (verified bit-exact R0-R2)
// ---------------------------------------------------------------------------
__device__ __forceinline__ unsigned int tf_bits(unsigned int x0, unsigned int x1) {
  const unsigned int K0 = 0u, K1 = 42u;
  const unsigned int KX = K0 ^ K1 ^ 0x1BD11BDAu;
  x0 += K0; x1 += K1;
#define TF_R(r) { x0 += x1; x1 = (x1 << (r)) | (x1 >> (32 - (r))); x1 ^= x0; }
  TF_R(13) TF_R(15) TF_R(26) TF_R(6)   x0 += K1; x1 += KX + 1u;
  TF_R(17) TF_R(29) TF_R(16) TF_R(24)  x0 += KX; x1 += K0 + 2u;
  TF_R(13) TF_R(15) TF_R(26) TF_R(6)   x0 += K0; x1 += K1 + 3u;
  TF_R(17) TF_R(29) TF_R(16) TF_R(24)  x0 += K1; x1 += KX + 4u;
  TF_R(13) TF_R(15) TF_R(26) TF_R(6)   x0 += KX; x1 += K0 + 5u;
#undef TF_R
  return x0 ^ x1;
}

__global__ __launch_bounds__(256) void k_dropout(const float* __restrict__ x,
                                                 unsigned short* __restrict__ xd) {
  const unsigned int base = (blockIdx.x * 256u + threadIdx.x) * 4u;
  const float4 xv = *reinterpret_cast<const float4*>(x + base);
  const float xs[4] = {xv.x, xv.y, xv.z, xv.w};
  us4 o;
#pragma unroll
  for (int j = 0; j < 4; ++j) {
    const unsigned int bits = tf_bits(0u, base + (unsigned int)j);
    const float u = __uint_as_float((bits >> 9) | 0x3f800000u) - 1.0f;
    const float v = (u < 0.9f) ? (xs[j] / 0.9f) : 0.0f;
    o[j] = f2bf(v);
  }
  *reinterpret_cast<us4*>(xd + base) = o;
}

__global__ __launch_bounds__(256) void k_pack_wi(const float* __restrict__ wi,
                                                 unsigned short* __restrict__ wit) {
  const int tid = blockIdx.x * 256 + threadIdx.x;
  const int n = tid >> 8, k = tid & 255;
  wit[n * 256 + k] = f2bf(wi[k * 1024 + n]);
}

__global__ __launch_bounds__(256) void k_colscale(const float* __restrict__ wh,
                                                  float* __restrict__ dq,
                                                  float* __restrict__ qs) {
  const int n = blockIdx.x * 256 + threadIdx.x;  // 0..1023
  float m = 0.f;
  for (int k = 0; k < 256; ++k) m = fmaxf(m, fabsf(wh[k * 1024 + n]));
  const float s = (m > 0.f) ? m : 1.f;
  dq[n] = s / 16129.0f;
  qs[n] = 127.0f / s;
}

// Wq packed in i8 MFMA-B fragment order (16x16x64) — layout validated R1/R2.
__global__ __launch_bounds__(256) void k_pack_wh_i8(const float* __restrict__ wh,
                                                    const float* __restrict__ qs,
                                                    signed char* __restrict__ wq) {
  const int tid = blockIdx.x * 256 + threadIdx.x;  // 0..262143
  const int j = tid & 15, l = (tid >> 4) & 63, kt = (tid >> 10) & 3, ntg = tid >> 12;
  const int k = kt * 64 + ((l >> 4) << 4) + j;
  const int n = ntg * 16 + (l & 15);
  float v = rintf(wh[k * 1024 + n] * qs[n]);
  v = fminf(fmaxf(v, -127.f), 127.f);
  wq[tid] = (signed char)(int)v;
}

// ---------------------------------------------------------------------------
// K2: Xp[t*64+b][n] = bf16(Xd @ Wi + b). Coalesced epilogue (32B runs).
// ---------------------------------------------------------------------------
__global__ __launch_bounds__(256) void k_gemm_x(const unsigned short* __restrict__ xd,
                                                const unsigned short* __restrict__ wit,
                                                const float* __restrict__ bias,
                                                unsigned short* __restrict__ xp) {
  __shared__ unsigned short As[2][128 * 40];
  __shared__ unsigned short Bs[2][128 * 40];
  const int tid = threadIdx.x;
  const int lane = tid & 63;
  const int wv = tid >> 6;
  const int wm = wv >> 1, wn = wv & 1;
  const int m0 = blockIdx.x * 128, n0 = blockIdx.y * 128;

  const int srow = tid >> 1, sseg = tid & 1;
  const unsigned short* gA = xd + (m0 + srow) * 256 + sseg * 16;
  const unsigned short* gB = wit + (n0 + srow) * 256 + sseg * 16;
  const int soff = srow * 40 + sseg * 16;

  const floatx4 zero4 = {0.f, 0.f, 0.f, 0.f};
  floatx4 acc[4][4];
#pragma unroll
  for (int i = 0; i < 4; ++i)
#pragma unroll
    for (int j = 0; j < 4; ++j) acc[i][j] = zero4;

  short8 ra0 = *(const short8*)(gA);
  short8 ra1 = *(const short8*)(gA + 8);
  short8 rb0 = *(const short8*)(gB);
  short8 rb1 = *(const short8*)(gB + 8);
  *(short8*)&As[0][soff] = ra0;
  *(short8*)&As[0][soff + 8] = ra1;
  *(short8*)&Bs[0][soff] = rb0;
  *(short8*)&Bs[0][soff + 8] = rb1;
  __syncthreads();

  const int frow = (lane & 15) * 40 + ((lane >> 4) << 3);
#pragma unroll 1
  for (int kt = 0; kt < 8; ++kt) {
    const int buf = kt & 1;
    if (kt < 7) {
      ra0 = *(const short8*)(gA + (kt + 1) * 32);
      ra1 = *(const short8*)(gA + (kt + 1) * 32 + 8);
      rb0 = *(const short8*)(gB + (kt + 1) * 32);
      rb1 = *(const short8*)(gB + (kt + 1) * 32 + 8);
    }
    short8 af[4], bfv[4];
#pragma unroll
    for (int mt = 0; mt < 4; ++mt)
      af[mt] = *(const short8*)&As[buf][(wm * 64 + mt * 16) * 40 + frow];
#pragma unroll
    for (int nt = 0; nt < 4; ++nt)
      bfv[nt] = *(const short8*)&Bs[buf][(wn * 64 + nt * 16) * 40 + frow];
#pragma unroll
    for (int mt = 0; mt < 4; ++mt)
#pragma unroll
      for (int nt = 0; nt < 4; ++nt)
        acc[mt][nt] = __builtin_amdgcn_mfma_f32_16x16x32_bf16(af[mt], bfv[nt], acc[mt][nt], 0, 0, 0);
    if (kt < 7) {
      *(short8*)&As[buf ^ 1][soff] = ra0;
      *(short8*)&As[buf ^ 1][soff + 8] = ra1;
      *(short8*)&Bs[buf ^ 1][soff] = rb0;
      *(short8*)&Bs[buf ^ 1][soff + 8] = rb1;
    }
    __syncthreads();
  }

#pragma unroll
  for (int nt = 0; nt < 4; ++nt) {
    const int gn = n0 + wn * 64 + nt * 16 + (lane & 15);
    const float bv = bias[gn];
#pragma unroll
    for (int mt = 0; mt < 4; ++mt) {
      const int mrow = m0 + wm * 64 + mt * 16 + ((lane >> 4) << 2);
#pragma unroll
      for (int q = 0; q < 4; ++q) {
        const int m = mrow + q;
        // row permutation: Xp row = t*64 + b  (m = b*2048 + t)
        xp[((size_t)(m & 2047) * 64 + (m >> 11)) * 1024 + gn] = f2bf(acc[mt][nt][q] + bv);
      }
    }
  }
}

// ---------------------------------------------------------------------------
// K3: weight-resident LSTM scan. 32 WGs x 2 batch rows, 1024 thr (16 waves,
// 4/SIMD). Wave v owns units [v*16, v*16+16): ntg(g) = g*16 + v.
// h duplicated into A-rows {0,4,8,12} = {b0,b1,b0,b1}; cell lands natively
// on its lane; lanes 32..63 are M-padding duplicates (masked off stores).
// ---------------------------------------------------------------------------
__global__ __launch_bounds__(1024) void k_lstm(const unsigned short* __restrict__ xp,
                                               const signed char* __restrict__ wq,
                                               const float* __restrict__ dq,
                                               const int* __restrict__ lens,
                                               float* __restrict__ out) {
  __shared__ __align__(16) signed char As[8192];  // 2 x [kt<4][alane<64][16] i8

  const int tid = threadIdx.x, lane = tid & 63, v = tid >> 6;
  const int wg = blockIdx.x, b0 = wg * 2;

  ((long long*)As)[tid] = 0;  // 1024*8 = 8192: zero both buffers

  // resident weights: 16 frags/lane (64 VGPR)
  int4v w[4][4];
#pragma unroll
  for (int g = 0; g < 4; ++g)
#pragma unroll
    for (int kt = 0; kt < 4; ++kt) {
      const int ntg = g * 16 + v;
      w[g][kt] = *(const int4v*)(wq + (size_t)(((ntg * 4 + kt) * 64 + lane)) * 16);
    }

  // cell geometry: 1 cell/lane; lanes 32..63 duplicate lanes 0..31
  const int r = (lane >> 4) & 1;
  const int u = v * 16 + (lane & 15);
  const bool valid = (lane < 32);

  float dqv[4];
#pragma unroll
  for (int g = 0; g < 4; ++g) dqv[g] = dq[g * 256 + u];
  const int lenm = lens[b0 + r] - 1;
  float c = 0.f, ckeep = 0.f, hkeep = 0.f;

  // LDS h-write byte offsets (A-rows r*4 and r*4+8)
  const int aw0 = (v >> 2) * 1024 + (((v & 3) * 16) + r * 4) * 16 + (lane & 15);
  const int aw1 = aw0 + 128;

  // running pointers: Xp row (t*64 + b) -> step stride 65536 elems
  const unsigned short* px = xp + (size_t)(b0 + r) * 1024 + u;
  float* po = out + 32768 + (size_t)(b0 + r) * 2048 * 256 + u;

  unsigned short xc0 = px[0], xc1 = px[256], xc2 = px[512], xc3 = px[768];
  px += 65536;

  __syncthreads();

  int curoff = 0;
  const float LOG2E = 1.44269504f;
  const int4v zacc = {0, 0, 0, 0};

#pragma unroll 1
  for (int t = 0; t < 2048; ++t) {
    // prefetch next step's 4 gate values (t=2047 reads WiT region: harmless)
    const unsigned short xn0 = px[0], xn1 = px[256], xn2 = px[512], xn3 = px[768];
    px += 65536;

    // A-fragments: first two now, rest interleaved with MFMA
    int4v af0 = *(const int4v*)&As[curoff + lane * 16];
    int4v af1 = *(const int4v*)&As[curoff + 1024 + lane * 16];

    int4v acc0, acc1, acc2, acc3;
    __builtin_amdgcn_s_setprio(1);
    acc0 = __builtin_amdgcn_mfma_i32_16x16x64_i8(af0, w[0][0], zacc, 0, 0, 0);
    acc1 = __builtin_amdgcn_mfma_i32_16x16x64_i8(af0, w[1][0], zacc, 0, 0, 0);
    acc2 = __builtin_amdgcn_mfma_i32_16x16x64_i8(af0, w[2][0], zacc, 0, 0, 0);
    acc3 = __builtin_amdgcn_mfma_i32_16x16x64_i8(af0, w[3][0], zacc, 0, 0, 0);
    int4v af2 = *(const int4v*)&As[curoff + 2048 + lane * 16];
    acc0 = __builtin_amdgcn_mfma_i32_16x16x64_i8(af1, w[0][1], acc0, 0, 0, 0);
    acc1 = __builtin_amdgcn_mfma_i32_16x16x64_i8(af1, w[1][1], acc1, 0, 0, 0);
    acc2 = __builtin_amdgcn_mfma_i32_16x16x64_i8(af1, w[2][1], acc2, 0, 0, 0);
    acc3 = __builtin_amdgcn_mfma_i32_16x16x64_i8(af1, w[3][1], acc3, 0, 0, 0);
    int4v af3 = *(const int4v*)&As[curoff + 3072 + lane * 16];
    acc0 = __builtin_amdgcn_mfma_i32_16x16x64_i8(af2, w[0][2], acc0, 0, 0, 0);
    acc1 = __builtin_amdgcn_mfma_i32_16x16x64_i8(af2, w[1][2], acc1, 0, 0, 0);
    acc2 = __builtin_amdgcn_mfma_i32_16x16x64_i8(af2, w[2][2], acc2, 0, 0, 0);
    acc3 = __builtin_amdgcn_mfma_i32_16x16x64_i8(af2, w[3][2], acc3, 0, 0, 0);
    acc0 = __builtin_amdgcn_mfma_i32_16x16x64_i8(af3, w[0][3], acc0, 0, 0, 0);
    acc1 = __builtin_amdgcn_mfma_i32_16x16x64_i8(af3, w[1][3], acc1, 0, 0, 0);
    acc2 = __builtin_amdgcn_mfma_i32_16x16x64_i8(af3, w[2][3], acc2, 0, 0, 0);
    acc3 = __builtin_amdgcn_mfma_i32_16x16x64_i8(af3, w[3][3], acc3, 0, 0, 0);
    __builtin_amdgcn_s_setprio(0);

    // gates: native placement (C reg 0, col lane&15)
    const float zi_ = fminf(fmaxf(fmaf((float)acc0[0], dqv[0], bf2f(xc0)), -20.f), 20.f);
    const float zf_ = fminf(fmaxf(fmaf((float)acc1[0], dqv[1], bf2f(xc1)), -20.f), 20.f);
    const float zg_ = fminf(fmaxf(fmaf((float)acc2[0], dqv[2], bf2f(xc2)), -20.f), 20.f);
    const float zo_ = fminf(fmaxf(fmaf((float)acc3[0], dqv[3], bf2f(xc3)), -20.f), 20.f);
    const float ei = fexp2(zi_ * LOG2E);
    const float e2g = fexp2(zg_ * (2.f * LOG2E));
    const float p1 = ei * (e2g - 1.f) * frcp((ei + 1.f) * (e2g + 1.f));
    const float ef = fexp2(-zf_ * LOG2E);
    const float cn = frcp(1.f + ef) * c + p1;
    c = cn;
    const float cc = fminf(fmaxf(cn, -15.f), 15.f);
    const float eo = fexp2(zo_ * LOG2E);
    const float e2c = fexp2(cc * (2.f * LOG2E));
    const float h = eo * (e2c - 1.f) * frcp((eo + 1.f) * (e2c + 1.f));

    if (valid) {
      float hq = rintf(h * 127.f);
      hq = fminf(fmaxf(hq, -127.f), 127.f);
      const signed char hb = (signed char)(int)hq;
      const int woff = curoff ^ 4096;
      As[woff + aw0] = hb;
      As[woff + aw1] = hb;
      *po = h;
      if (t == lenm) { ckeep = cn; hkeep = h; }
    }
    po += 256;

    xc0 = xn0; xc1 = xn1; xc2 = xn2; xc3 = xn3;
    __syncthreads();
    curoff ^= 4096;
  }

  if (valid) {
    out[(size_t)(b0 + r) * 256 + u] = ckeep;
    out[16384 + (size_t)(b0 + r) * 256 + u] = hkeep;
  }
}

// ---------------------------------------------------------------------------
extern "C" void kernel_launch(void* const* d_in, const int* in_sizes, int n_in,
                              void* d_out, int out_size, void* d_ws, size_t ws_size,
                              hipStream_t stream) {
  (void)in_sizes; (void)n_in; (void)out_size; (void)ws_size;
  const float* x = (const float*)d_in[0];
  const float* wi = (const float*)d_in[1];
  const float* wh = (const float*)d_in[2];
  const float* bias = (const float*)d_in[3];
  const int* lens = (const int*)d_in[4];
  float* out = (float*)d_out;

  char* ws = (char*)d_ws;
  unsigned short* xd = (unsigned short*)ws;                         // 64 MiB
  unsigned short* xp = (unsigned short*)(ws + 67108864ull);         // 256 MiB
  unsigned short* wit = (unsigned short*)(ws + 335544320ull);       // 512 KiB
  float* dq = (float*)(ws + 336068608ull);                          // 4 KiB
  float* qs = (float*)(ws + 336072704ull);                          // 4 KiB
  signed char* wqb = (signed char*)(ws + 336076800ull);             // 256 KiB

  k_pack_wi<<<1024, 256, 0, stream>>>(wi, wit);
  k_colscale<<<4, 256, 0, stream>>>(wh, dq, qs);
  k_pack_wh_i8<<<1024, 256, 0, stream>>>(wh, qs, wqb);
  k_dropout<<<32768, 256, 0, stream>>>(x, xd);
  k_gemm_x<<<dim3(1024, 8), 256, 0, stream>>>(xd, wit, bias, xp);
  k_lstm<<<32, 1024, 0, stream>>>(xp, wqb, dq, lens, out);
}

// Round 5
// 1904.630 us; speedup vs baseline: 1.1301x; 1.1301x over previous
//
#include <hip/hip_runtime.h>

// ============================================================================
// UnidirecLSTMLayerWithDropoutBefore: dropout(Threefry) -> x@Wi GEMM -> LSTM
// B=64, T=2048, D=256, H=256, gates (i,f,g,o), dropout 0.1, key 42.
//
// R4 = R2 k_lstm geometry (512 thr / 8 waves / 32 WGs x 2 rows, every lane a
// real cell) + R3's coalesced Xp layout [t*64+b][gate*256+u] (non-lstm time
// 554->264 us) + setprio around MFMA + register-kept finals.
// R3's 16-wave variant regressed: duplicate lanes doubled gate VALU (800->1460
// cyc/step). MFMA pipe floor for this structure: 64/SIMD/step ~ 1306 cyc.
//
// ws layout (bytes):
//   [0, 64MiB)            Xd   bf16 [131072][256]
//   [64MiB, 320MiB)       Xp   bf16 [t*64+b][1024]  (n = gate*256 + u)
//   [335544320, +512KiB)  WiT  bf16 [1024][256]
//   [336068608, +4KiB)    dq   f32 [1024]
//   [336072704, +4KiB)    qs   f32 [1024]
//   [336076800, +256KiB)  Wq   i8 packed MFMA-B frags [ntg][kt][lane][16]
// Output f32: c_last[16384] | h_last[16384] | outputs[64*2048*256]
// ============================================================================

typedef __attribute__((ext_vector_type(8))) short short8;
typedef __attribute__((ext_vector_type(4))) float floatx4;
typedef __attribute__((ext_vector_type(4))) int int4v;
typedef __attribute__((ext_vector_type(4))) unsigned short us4;

__device__ __forceinline__ unsigned short f2bf(float f) {
  unsigned int u = __float_as_uint(f);
  u = u + 0x7fffu + ((u >> 16) & 1u);   // RNE
  return (unsigned short)(u >> 16);
}
__device__ __forceinline__ float bf2f(unsigned short s) {
  return __uint_as_float(((unsigned int)s) << 16);
}
__device__ __forceinline__ float fexp2(float x) { return __builtin_amdgcn_exp2f(x); }
__device__ __forceinline__ float frcp(float x) { return __builtin_amdgcn_rcpf(x); }

// ---------------------------------------------------------------------------
// Threefry-2x32, key (0,42), partitionable scheme (verified bit-exact R0-R3)
// ---------------------------------------------------------------------------
__device__ __forceinline__ unsigned int tf_bits(unsigned int x0, unsigned int x1) {
  const unsigned int K0 = 0u, K1 = 42u;
  const unsigned int KX = K0 ^ K1 ^ 0x1BD11BDAu;
  x0 += K0; x1 += K1;
#define TF_R(r) { x0 += x1; x1 = (x1 << (r)) | (x1 >> (32 - (r))); x1 ^= x0; }
  TF_R(13) TF_R(15) TF_R(26) TF_R(6)   x0 += K1; x1 += KX + 1u;
  TF_R(17) TF_R(29) TF_R(16) TF_R(24)  x0 += KX; x1 += K0 + 2u;
  TF_R(13) TF_R(15) TF_R(26) TF_R(6)   x0 += K0; x1 += K1 + 3u;
  TF_R(17) TF_R(29) TF_R(16) TF_R(24)  x0 += K1; x1 += KX + 4u;
  TF_R(13) TF_R(15) TF_R(26) TF_R(6)   x0 += KX; x1 += K0 + 5u;
#undef TF_R
  return x0 ^ x1;
}

__global__ __launch_bounds__(256) void k_dropout(const float* __restrict__ x,
                                                 unsigned short* __restrict__ xd) {
  const unsigned int base = (blockIdx.x * 256u + threadIdx.x) * 4u;
  const float4 xv = *reinterpret_cast<const float4*>(x + base);
  const float xs[4] = {xv.x, xv.y, xv.z, xv.w};
  us4 o;
#pragma unroll
  for (int j = 0; j < 4; ++j) {
    const unsigned int bits = tf_bits(0u, base + (unsigned int)j);
    const float u = __uint_as_float((bits >> 9) | 0x3f800000u) - 1.0f;
    const float v = (u < 0.9f) ? (xs[j] / 0.9f) : 0.0f;
    o[j] = f2bf(v);
  }
  *reinterpret_cast<us4*>(xd + base) = o;
}

__global__ __launch_bounds__(256) void k_pack_wi(const float* __restrict__ wi,
                                                 unsigned short* __restrict__ wit) {
  const int tid = blockIdx.x * 256 + threadIdx.x;
  const int n = tid >> 8, k = tid & 255;
  wit[n * 256 + k] = f2bf(wi[k * 1024 + n]);
}

__global__ __launch_bounds__(256) void k_colscale(const float* __restrict__ wh,
                                                  float* __restrict__ dq,
                                                  float* __restrict__ qs) {
  const int n = blockIdx.x * 256 + threadIdx.x;  // 0..1023
  float m = 0.f;
  for (int k = 0; k < 256; ++k) m = fmaxf(m, fabsf(wh[k * 1024 + n]));
  const float s = (m > 0.f) ? m : 1.f;
  dq[n] = s / 16129.0f;
  qs[n] = 127.0f / s;
}

// Wq packed in i8 MFMA-B fragment order (16x16x64) — layout validated R1-R3.
__global__ __launch_bounds__(256) void k_pack_wh_i8(const float* __restrict__ wh,
                                                    const float* __restrict__ qs,
                                                    signed char* __restrict__ wq) {
  const int tid = blockIdx.x * 256 + threadIdx.x;  // 0..262143
  const int j = tid & 15, l = (tid >> 4) & 63, kt = (tid >> 10) & 3, ntg = tid >> 12;
  const int k = kt * 64 + ((l >> 4) << 4) + j;
  const int n = ntg * 16 + (l & 15);
  float v = rintf(wh[k * 1024 + n] * qs[n]);
  v = fminf(fmaxf(v, -127.f), 127.f);
  wq[tid] = (signed char)(int)v;
}

// ---------------------------------------------------------------------------
// K2: Xp[t*64+b][n] = bf16(Xd @ Wi + b). Coalesced epilogue (32B runs).
// ---------------------------------------------------------------------------
__global__ __launch_bounds__(256) void k_gemm_x(const unsigned short* __restrict__ xd,
                                                const unsigned short* __restrict__ wit,
                                                const float* __restrict__ bias,
                                                unsigned short* __restrict__ xp) {
  __shared__ unsigned short As[2][128 * 40];
  __shared__ unsigned short Bs[2][128 * 40];
  const int tid = threadIdx.x;
  const int lane = tid & 63;
  const int wv = tid >> 6;
  const int wm = wv >> 1, wn = wv & 1;
  const int m0 = blockIdx.x * 128, n0 = blockIdx.y * 128;

  const int srow = tid >> 1, sseg = tid & 1;
  const unsigned short* gA = xd + (m0 + srow) * 256 + sseg * 16;
  const unsigned short* gB = wit + (n0 + srow) * 256 + sseg * 16;
  const int soff = srow * 40 + sseg * 16;

  const floatx4 zero4 = {0.f, 0.f, 0.f, 0.f};
  floatx4 acc[4][4];
#pragma unroll
  for (int i = 0; i < 4; ++i)
#pragma unroll
    for (int j = 0; j < 4; ++j) acc[i][j] = zero4;

  short8 ra0 = *(const short8*)(gA);
  short8 ra1 = *(const short8*)(gA + 8);
  short8 rb0 = *(const short8*)(gB);
  short8 rb1 = *(const short8*)(gB + 8);
  *(short8*)&As[0][soff] = ra0;
  *(short8*)&As[0][soff + 8] = ra1;
  *(short8*)&Bs[0][soff] = rb0;
  *(short8*)&Bs[0][soff + 8] = rb1;
  __syncthreads();

  const int frow = (lane & 15) * 40 + ((lane >> 4) << 3);
#pragma unroll 1
  for (int kt = 0; kt < 8; ++kt) {
    const int buf = kt & 1;
    if (kt < 7) {
      ra0 = *(const short8*)(gA + (kt + 1) * 32);
      ra1 = *(const short8*)(gA + (kt + 1) * 32 + 8);
      rb0 = *(const short8*)(gB + (kt + 1) * 32);
      rb1 = *(const short8*)(gB + (kt + 1) * 32 + 8);
    }
    short8 af[4], bfv[4];
#pragma unroll
    for (int mt = 0; mt < 4; ++mt)
      af[mt] = *(const short8*)&As[buf][(wm * 64 + mt * 16) * 40 + frow];
#pragma unroll
    for (int nt = 0; nt < 4; ++nt)
      bfv[nt] = *(const short8*)&Bs[buf][(wn * 64 + nt * 16) * 40 + frow];
#pragma unroll
    for (int mt = 0; mt < 4; ++mt)
#pragma unroll
      for (int nt = 0; nt < 4; ++nt)
        acc[mt][nt] = __builtin_amdgcn_mfma_f32_16x16x32_bf16(af[mt], bfv[nt], acc[mt][nt], 0, 0, 0);
    if (kt < 7) {
      *(short8*)&As[buf ^ 1][soff] = ra0;
      *(short8*)&As[buf ^ 1][soff + 8] = ra1;
      *(short8*)&Bs[buf ^ 1][soff] = rb0;
      *(short8*)&Bs[buf ^ 1][soff + 8] = rb1;
    }
    __syncthreads();
  }

#pragma unroll
  for (int nt = 0; nt < 4; ++nt) {
    const int gn = n0 + wn * 64 + nt * 16 + (lane & 15);
    const float bv = bias[gn];
#pragma unroll
    for (int mt = 0; mt < 4; ++mt) {
      const int mrow = m0 + wm * 64 + mt * 16 + ((lane >> 4) << 2);
#pragma unroll
      for (int q = 0; q < 4; ++q) {
        const int m = mrow + q;
        // row permutation: Xp row = t*64 + b  (m = b*2048 + t)
        xp[((size_t)(m & 2047) * 64 + (m >> 11)) * 1024 + gn] = f2bf(acc[mt][nt][q] + bv);
      }
    }
  }
}

// ---------------------------------------------------------------------------
// K3: weight-resident LSTM scan. 32 WGs x 2 batch rows, 512 thr (8 waves,
// 2/SIMD). Wave v owns units [v*32, v*32+32): ntg(g,p) = g*16 + v*2 + p.
// h duplicated into A-rows {0,4,8,12} = {b0,b1,b0,b1}; cell (r,u) lands
// natively on its lane (C reg 0); p-half select = 1 cndmask per gate.
// All 64 lanes are real cells (R3 lesson: no duplicate-lane gate work).
// ---------------------------------------------------------------------------
__global__ __launch_bounds__(512, 2) void k_lstm(const unsigned short* __restrict__ xp,
                                                 const signed char* __restrict__ wq,
                                                 const float* __restrict__ dq,
                                                 const int* __restrict__ lens,
                                                 float* __restrict__ out) {
  __shared__ __align__(16) signed char As[8192];  // 2 x [kt<4][alane<64][16] i8

  const int tid = threadIdx.x, lane = tid & 63, v = tid >> 6;
  const int wg = blockIdx.x, b0 = wg * 2;

  const int4v zacc = {0, 0, 0, 0};
  ((int4v*)As)[tid] = zacc;  // 512*16 = 8192: zero both buffers

  // resident weights: 32 frags/lane (128 VGPR)
  int4v w[4][2][4];
#pragma unroll
  for (int g = 0; g < 4; ++g)
#pragma unroll
    for (int p = 0; p < 2; ++p)
#pragma unroll
      for (int kt = 0; kt < 4; ++kt) {
        const int ntg = g * 16 + v * 2 + p;
        w[g][p][kt] = *(const int4v*)(wq + (size_t)(((ntg * 4 + kt) * 64 + lane)) * 16);
      }

  // cell geometry: 1 cell/lane, all lanes useful
  const int r = (lane >> 4) & 1;          // batch row within WG
  const int ph = lane >> 5;               // p-half select
  const int u = v * 32 + ph * 16 + (lane & 15);

  float dqv[4];
#pragma unroll
  for (int g = 0; g < 4; ++g) dqv[g] = dq[g * 256 + u];
  const int lenm = lens[b0 + r] - 1;
  float c = 0.f, ckeep = 0.f, hkeep = 0.f;

  // fixed LDS h-write byte offsets (A-rows r*4 and r*4+8), within one buffer
  const int aw0 = (u >> 6) * 1024 + (((u >> 4) & 3) * 16 + r * 4) * 16 + (u & 15);
  const int aw1 = aw0 + 128;

  // running pointers: Xp row = t*64 + b, gates at n = g*256 + u
  const unsigned short* px = xp + (size_t)(b0 + r) * 1024 + u;
  float* po = out + 32768 + (size_t)(b0 + r) * 2048 * 256 + u;

  unsigned short xc0 = px[0], xc1 = px[256], xc2 = px[512], xc3 = px[768];
  px += 65536;

  __syncthreads();

  int curoff = 0;
  const float LOG2E = 1.44269504f;

#pragma unroll 1
  for (int t = 0; t < 2048; ++t) {
    // prefetch next step's gate slice (t=2047 reads past Xp: harmless ws data)
    const unsigned short xn0 = px[0], xn1 = px[256], xn2 = px[512], xn3 = px[768];
    px += 65536;

    // A-fragments from current buffer
    int4v af0 = *(const int4v*)&As[curoff + lane * 16];
    int4v af1 = *(const int4v*)&As[curoff + 1024 + lane * 16];
    int4v af2 = *(const int4v*)&As[curoff + 2048 + lane * 16];
    int4v af3 = *(const int4v*)&As[curoff + 3072 + lane * 16];

    int4v acc[4][2];
    __builtin_amdgcn_s_setprio(1);
#pragma unroll
    for (int g = 0; g < 4; ++g)
#pragma unroll
      for (int p = 0; p < 2; ++p) {
        acc[g][p] = __builtin_amdgcn_mfma_i32_16x16x64_i8(af0, w[g][p][0], zacc, 0, 0, 0);
        acc[g][p] = __builtin_amdgcn_mfma_i32_16x16x64_i8(af1, w[g][p][1], acc[g][p], 0, 0, 0);
        acc[g][p] = __builtin_amdgcn_mfma_i32_16x16x64_i8(af2, w[g][p][2], acc[g][p], 0, 0, 0);
        acc[g][p] = __builtin_amdgcn_mfma_i32_16x16x64_i8(af3, w[g][p][3], acc[g][p], 0, 0, 0);
      }
    __builtin_amdgcn_s_setprio(0);

    // gates: native placement (C reg 0), p-half via cndmask
    const int zi0 = (ph == 0) ? acc[0][0][0] : acc[0][1][0];
    const int zi1 = (ph == 0) ? acc[1][0][0] : acc[1][1][0];
    const int zi2 = (ph == 0) ? acc[2][0][0] : acc[2][1][0];
    const int zi3 = (ph == 0) ? acc[3][0][0] : acc[3][1][0];
    const float zi_ = fminf(fmaxf(fmaf((float)zi0, dqv[0], bf2f(xc0)), -20.f), 20.f);
    const float zf_ = fminf(fmaxf(fmaf((float)zi1, dqv[1], bf2f(xc1)), -20.f), 20.f);
    const float zg_ = fminf(fmaxf(fmaf((float)zi2, dqv[2], bf2f(xc2)), -20.f), 20.f);
    const float zo_ = fminf(fmaxf(fmaf((float)zi3, dqv[3], bf2f(xc3)), -20.f), 20.f);
    const float ei = fexp2(zi_ * LOG2E);
    const float e2g = fexp2(zg_ * (2.f * LOG2E));
    const float p1 = ei * (e2g - 1.f) * frcp((ei + 1.f) * (e2g + 1.f));
    const float ef = fexp2(-zf_ * LOG2E);
    const float cn = frcp(1.f + ef) * c + p1;
    c = cn;
    const float cc = fminf(fmaxf(cn, -15.f), 15.f);
    const float eo = fexp2(zo_ * LOG2E);
    const float e2c = fexp2(cc * (2.f * LOG2E));
    const float h = eo * (e2c - 1.f) * frcp((eo + 1.f) * (e2c + 1.f));

    // h -> i8, duplicated A-rows in the other buffer
    float hq = rintf(h * 127.f);
    hq = fminf(fmaxf(hq, -127.f), 127.f);
    const signed char hb = (signed char)(int)hq;
    const int woff = curoff ^ 4096;
    As[woff + aw0] = hb;
    As[woff + aw1] = hb;

    *po = h;
    po += 256;
    if (t == lenm) { ckeep = cn; hkeep = h; }  // 2 cndmask, no store

    xc0 = xn0; xc1 = xn1; xc2 = xn2; xc3 = xn3;
    __syncthreads();
    curoff ^= 4096;
  }

  out[(size_t)(b0 + r) * 256 + u] = ckeep;
  out[16384 + (size_t)(b0 + r) * 256 + u] = hkeep;
}

// ---------------------------------------------------------------------------
extern "C" void kernel_launch(void* const* d_in, const int* in_sizes, int n_in,
                              void* d_out, int out_size, void* d_ws, size_t ws_size,
                              hipStream_t stream) {
  (void)in_sizes; (void)n_in; (void)out_size; (void)ws_size;
  const float* x = (const float*)d_in[0];
  const float* wi = (const float*)d_in[1];
  const float* wh = (const float*)d_in[2];
  const float* bias = (const float*)d_in[3];
  const int* lens = (const int*)d_in[4];
  float* out = (float*)d_out;

  char* ws = (char*)d_ws;
  unsigned short* xd = (unsigned short*)ws;                         // 64 MiB
  unsigned short* xp = (unsigned short*)(ws + 67108864ull);         // 256 MiB
  unsigned short* wit = (unsigned short*)(ws + 335544320ull);       // 512 KiB
  float* dq = (float*)(ws + 336068608ull);                          // 4 KiB
  float* qs = (float*)(ws + 336072704ull);                          // 4 KiB
  signed char* wqb = (signed char*)(ws + 336076800ull);             // 256 KiB

  k_pack_wi<<<1024, 256, 0, stream>>>(wi, wit);
  k_colscale<<<4, 256, 0, stream>>>(wh, dq, qs);
  k_pack_wh_i8<<<1024, 256, 0, stream>>>(wh, qs, wqb);
  k_dropout<<<32768, 256, 0, stream>>>(x, xd);
  k_gemm_x<<<dim3(1024, 8), 256, 0, stream>>>(xd, wit, bias, xp);
  k_lstm<<<32, 512, 0, stream>>>(xp, wqb, dq, lens, out);
}

// Round 6
// 1640.855 us; speedup vs baseline: 1.3118x; 1.1608x over previous
//
#include <hip/hip_runtime.h>

// ============================================================================
// UnidirecLSTMLayerWithDropoutBefore: dropout(Threefry) -> x@Wi GEMM -> LSTM
// B=64, T=2048, D=256, H=256, gates (i,f,g,o), dropout 0.1, key 42.
//
// R5: k_lstm = R2-exact structure (512thr/8waves/32WGx2rows, one us4 Xp read
// per lane/step, no setprio) -- R2 measured 1635 cyc/step. Gemm N-tile spans
// all 4 gates (32 units x 4 gates) with LDS-restaged epilogue, so Xp is
// us4 gate-interleaved [t*64+b][u][g] AND gemm stores stay coalesced.
// R4 lesson: 4 scalar 2B Xp loads/step cost +280 cyc/step vs one us4.
// R3 lesson: duplicate-lane gate work doubles VALU. MFMA floor 1306 cyc/step.
//
// ws layout (bytes):
//   [0, 64MiB)            Xd   bf16 [131072][256]
//   [64MiB, 320MiB)       Xp   bf16 [t*64+b][u*4+g]  (us4 per (row,u))
//   [335544320, +512KiB)  WiT  bf16 [1024][256]
//   [336068608, +4KiB)    dq   f32 [1024]
//   [336072704, +4KiB)    qs   f32 [1024]
//   [336076800, +256KiB)  Wq   i8 packed MFMA-B frags [ntg][kt][lane][16]
// Output f32: c_last[16384] | h_last[16384] | outputs[64*2048*256]
// ============================================================================

typedef __attribute__((ext_vector_type(8))) short short8;
typedef __attribute__((ext_vector_type(4))) float floatx4;
typedef __attribute__((ext_vector_type(4))) int int4v;
typedef __attribute__((ext_vector_type(4))) unsigned short us4;

__device__ __forceinline__ unsigned short f2bf(float f) {
  unsigned int u = __float_as_uint(f);
  u = u + 0x7fffu + ((u >> 16) & 1u);   // RNE
  return (unsigned short)(u >> 16);
}
__device__ __forceinline__ float bf2f(unsigned short s) {
  return __uint_as_float(((unsigned int)s) << 16);
}
__device__ __forceinline__ float fexp2(float x) { return __builtin_amdgcn_exp2f(x); }
__device__ __forceinline__ float frcp(float x) { return __builtin_amdgcn_rcpf(x); }

// ---------------------------------------------------------------------------
// Threefry-2x32, key (0,42), partitionable scheme (verified bit-exact R0-R4)
// ---------------------------------------------------------------------------
__device__ __forceinline__ unsigned int tf_bits(unsigned int x0, unsigned int x1) {
  const unsigned int K0 = 0u, K1 = 42u;
  const unsigned int KX = K0 ^ K1 ^ 0x1BD11BDAu;
  x0 += K0; x1 += K1;
#define TF_R(r) { x0 += x1; x1 = (x1 << (r)) | (x1 >> (32 - (r))); x1 ^= x0; }
  TF_R(13) TF_R(15) TF_R(26) TF_R(6)   x0 += K1; x1 += KX + 1u;
  TF_R(17) TF_R(29) TF_R(16) TF_R(24)  x0 += KX; x1 += K0 + 2u;
  TF_R(13) TF_R(15) TF_R(26) TF_R(6)   x0 += K0; x1 += K1 + 3u;
  TF_R(17) TF_R(29) TF_R(16) TF_R(24)  x0 += K1; x1 += KX + 4u;
  TF_R(13) TF_R(15) TF_R(26) TF_R(6)   x0 += KX; x1 += K0 + 5u;
#undef TF_R
  return x0 ^ x1;
}

__global__ __launch_bounds__(256) void k_dropout(const float* __restrict__ x,
                                                 unsigned short* __restrict__ xd) {
  const unsigned int base = (blockIdx.x * 256u + threadIdx.x) * 4u;
  const float4 xv = *reinterpret_cast<const float4*>(x + base);
  const float xs[4] = {xv.x, xv.y, xv.z, xv.w};
  us4 o;
#pragma unroll
  for (int j = 0; j < 4; ++j) {
    const unsigned int bits = tf_bits(0u, base + (unsigned int)j);
    const float u = __uint_as_float((bits >> 9) | 0x3f800000u) - 1.0f;
    const float v = (u < 0.9f) ? (xs[j] / 0.9f) : 0.0f;
    o[j] = f2bf(v);
  }
  *reinterpret_cast<us4*>(xd + base) = o;
}

__global__ __launch_bounds__(256) void k_pack_wi(const float* __restrict__ wi,
                                                 unsigned short* __restrict__ wit) {
  const int tid = blockIdx.x * 256 + threadIdx.x;
  const int n = tid >> 8, k = tid & 255;
  wit[n * 256 + k] = f2bf(wi[k * 1024 + n]);
}

__global__ __launch_bounds__(256) void k_colscale(const float* __restrict__ wh,
                                                  float* __restrict__ dq,
                                                  float* __restrict__ qs) {
  const int n = blockIdx.x * 256 + threadIdx.x;  // 0..1023
  float m = 0.f;
  for (int k = 0; k < 256; ++k) m = fmaxf(m, fabsf(wh[k * 1024 + n]));
  const float s = (m > 0.f) ? m : 1.f;
  dq[n] = s / 16129.0f;
  qs[n] = 127.0f / s;
}

// Wq packed in i8 MFMA-B fragment order (16x16x64) — layout validated R1-R4.
__global__ __launch_bounds__(256) void k_pack_wh_i8(const float* __restrict__ wh,
                                                    const float* __restrict__ qs,
                                                    signed char* __restrict__ wq) {
  const int tid = blockIdx.x * 256 + threadIdx.x;  // 0..262143
  const int j = tid & 15, l = (tid >> 4) & 63, kt = (tid >> 10) & 3, ntg = tid >> 12;
  const int k = kt * 64 + ((l >> 4) << 4) + j;
  const int n = ntg * 16 + (l & 15);
  float v = rintf(wh[k * 1024 + n] * qs[n]);
  v = fminf(fmaxf(v, -127.f), 127.f);
  wq[tid] = (signed char)(int)v;
}

// ---------------------------------------------------------------------------
// K2: Xp[t*64+b][u*4+g] = bf16(Xd @ Wi + b).
// Block = 128 rows x (32 units x 4 gates). N-col jj (gate-major): gate=jj>>5,
// unit = y*32 + (jj&31). Epilogue restages C via LDS -> coalesced us4 stores.
// ---------------------------------------------------------------------------
__global__ __launch_bounds__(256) void k_gemm_x(const unsigned short* __restrict__ xd,
                                                const unsigned short* __restrict__ wit,
                                                const float* __restrict__ bias,
                                                unsigned short* __restrict__ xp) {
  // staging: A[2][5120] = SH[0..10240), B[2][5120] = SH[10240..20480)
  // epilogue: C[128][132] = SH[0..16896)
  __shared__ unsigned short SH[20480];
  const int tid = threadIdx.x;
  const int lane = tid & 63;
  const int wv = tid >> 6;
  const int wm = wv >> 1, wn = wv & 1;
  const int m0 = blockIdx.x * 128;
  const int y = blockIdx.y;  // unit block: units [y*32, y*32+32)

  const int srow = tid >> 1, sseg = tid & 1;
  const unsigned short* gA = xd + (m0 + srow) * 256 + sseg * 16;
  // B source: wit row n(srow) = (srow>>5)*256 + y*32 + (srow&31)
  const int nsrc = ((srow >> 5) << 8) + y * 32 + (srow & 31);
  const unsigned short* gB = wit + nsrc * 256 + sseg * 16;
  const int soff = srow * 40 + sseg * 16;

  const floatx4 zero4 = {0.f, 0.f, 0.f, 0.f};
  floatx4 acc[4][4];
#pragma unroll
  for (int i = 0; i < 4; ++i)
#pragma unroll
    for (int j = 0; j < 4; ++j) acc[i][j] = zero4;

  short8 ra0 = *(const short8*)(gA);
  short8 ra1 = *(const short8*)(gA + 8);
  short8 rb0 = *(const short8*)(gB);
  short8 rb1 = *(const short8*)(gB + 8);
  *(short8*)&SH[soff] = ra0;
  *(short8*)&SH[soff + 8] = ra1;
  *(short8*)&SH[10240 + soff] = rb0;
  *(short8*)&SH[10240 + soff + 8] = rb1;
  __syncthreads();

  const int frow = (lane & 15) * 40 + ((lane >> 4) << 3);
#pragma unroll 1
  for (int kt = 0; kt < 8; ++kt) {
    const int boff = (kt & 1) * 5120;
    if (kt < 7) {
      ra0 = *(const short8*)(gA + (kt + 1) * 32);
      ra1 = *(const short8*)(gA + (kt + 1) * 32 + 8);
      rb0 = *(const short8*)(gB + (kt + 1) * 32);
      rb1 = *(const short8*)(gB + (kt + 1) * 32 + 8);
    }
    short8 af[4], bfv[4];
#pragma unroll
    for (int mt = 0; mt < 4; ++mt)
      af[mt] = *(const short8*)&SH[boff + (wm * 64 + mt * 16) * 40 + frow];
#pragma unroll
    for (int nt = 0; nt < 4; ++nt)
      bfv[nt] = *(const short8*)&SH[10240 + boff + (wn * 64 + nt * 16) * 40 + frow];
#pragma unroll
    for (int mt = 0; mt < 4; ++mt)
#pragma unroll
      for (int nt = 0; nt < 4; ++nt)
        acc[mt][nt] = __builtin_amdgcn_mfma_f32_16x16x32_bf16(af[mt], bfv[nt], acc[mt][nt], 0, 0, 0);
    if (kt < 7) {
      const int noff = (boff ^ 5120);
      *(short8*)&SH[noff + soff] = ra0;
      *(short8*)&SH[noff + soff + 8] = ra1;
      *(short8*)&SH[10240 + noff + soff] = rb0;
      *(short8*)&SH[10240 + noff + soff + 8] = rb1;
    }
    __syncthreads();
  }

  // bias per nt: gate = wn*2 + (nt>>1), unit = y*32 + (nt&1)*16 + (lane&15)
  float bv[4];
#pragma unroll
  for (int nt = 0; nt < 4; ++nt)
    bv[nt] = bias[((wn * 2 + (nt >> 1)) << 8) + y * 32 + ((nt & 1) << 4) + (lane & 15)];

  // restage C through LDS: Cs[row][jj], row-major 132 pitch
  __syncthreads();
#pragma unroll
  for (int mt = 0; mt < 4; ++mt) {
#pragma unroll
    for (int nt = 0; nt < 4; ++nt) {
      const int jj = wn * 64 + nt * 16 + (lane & 15);
#pragma unroll
      for (int q = 0; q < 4; ++q) {
        const int row = wm * 64 + mt * 16 + ((lane >> 4) << 2) + q;
        SH[row * 132 + jj] = f2bf(acc[mt][nt][q] + bv[nt]);
      }
    }
  }
  __syncthreads();

  // coalesced us4 stores: thread k*256+tid -> (row = pi>>5, u = pi&31)
#pragma unroll
  for (int k = 0; k < 16; ++k) {
    const int pi = k * 256 + tid;
    const int row = pi >> 5, u = pi & 31;
    us4 o = {SH[row * 132 + u], SH[row * 132 + 32 + u],
             SH[row * 132 + 64 + u], SH[row * 132 + 96 + u]};
    const int m = m0 + row;
    *(us4*)(xp + ((size_t)(m & 2047) * 64 + (m >> 11)) * 1024 +
            (size_t)(y * 32 + u) * 4) = o;
  }
}

// ---------------------------------------------------------------------------
// K3: weight-resident LSTM scan — R2-exact structure (measured 1635 cyc/step).
// 32 WGs x 2 batch rows, 512 thr (8 waves, 2/SIMD). Wave v owns units
// [v*32, v*32+32): ntg(g,p) = g*16 + v*2 + p. h duplicated into A-rows
// {0,4,8,12} = {b0,b1,b0,b1}; cell lands natively on its lane (C reg 0);
// p-half select = 1 cndmask/gate. One us4 Xp load per lane per step.
// ---------------------------------------------------------------------------
__global__ __launch_bounds__(512, 2) void k_lstm(const unsigned short* __restrict__ xp,
                                                 const signed char* __restrict__ wq,
                                                 const float* __restrict__ dq,
                                                 const int* __restrict__ lens,
                                                 float* __restrict__ out) {
  __shared__ __align__(16) signed char As[8192];  // 2 x [kt<4][alane<64][16] i8

  const int tid = threadIdx.x, lane = tid & 63, v = tid >> 6;
  const int wg = blockIdx.x, b0 = wg * 2;

  const int4v zacc = {0, 0, 0, 0};
  ((int4v*)As)[tid] = zacc;  // 512*16 = 8192: zero both buffers

  // resident weights: 32 frags/lane (128 VGPR)
  int4v w[4][2][4];
#pragma unroll
  for (int g = 0; g < 4; ++g)
#pragma unroll
    for (int p = 0; p < 2; ++p)
#pragma unroll
      for (int kt = 0; kt < 4; ++kt) {
        const int ntg = g * 16 + v * 2 + p;
        w[g][p][kt] = *(const int4v*)(wq + (size_t)(((ntg * 4 + kt) * 64 + lane)) * 16);
      }

  // cell geometry: 1 cell/lane, all 64 lanes real
  const int r = (lane >> 4) & 1;          // batch row within WG
  const int ph = lane >> 5;               // p-half select
  const int u = v * 32 + ph * 16 + (lane & 15);

  float dqv[4];
#pragma unroll
  for (int g = 0; g < 4; ++g) dqv[g] = dq[g * 256 + u];
  const int lenm = lens[b0 + r] - 1;
  float c = 0.f;

  // fixed LDS h-write byte offsets (A-rows r*4 and r*4+8)
  const int aw0 = (u >> 6) * 1024 + (((u >> 4) & 3) * 16 + r * 4) * 16 + (u & 15);
  const int aw1 = aw0 + 128;

  // running pointers: Xp row = t*64 + b, us4 at (row*1024 + u*4)
  const unsigned short* px = xp + (size_t)(b0 + r) * 1024 + u * 4;
  float* po = out + 32768 + (size_t)(b0 + r) * 2048 * 256 + u;
  float* pc = out + (size_t)(b0 + r) * 256 + u;
  float* phl = pc + 16384;

  us4 xc = *(const us4*)px;
  px += 65536;

  __syncthreads();

  int curoff = 0;
  const float LOG2E = 1.44269504f;

#pragma unroll 1
  for (int t = 0; t < 2048; ++t) {
    // prefetch next step's gate us4 (t=2047 reads into WiT region: harmless)
    const us4 xn = *(const us4*)px;
    px += 65536;

    // A-fragments from current buffer
    int4v af0 = *(const int4v*)&As[curoff + lane * 16];
    int4v af1 = *(const int4v*)&As[curoff + 1024 + lane * 16];
    int4v af2 = *(const int4v*)&As[curoff + 2048 + lane * 16];
    int4v af3 = *(const int4v*)&As[curoff + 3072 + lane * 16];

    int4v acc[4][2];
#pragma unroll
    for (int g = 0; g < 4; ++g)
#pragma unroll
      for (int p = 0; p < 2; ++p) {
        acc[g][p] = __builtin_amdgcn_mfma_i32_16x16x64_i8(af0, w[g][p][0], zacc, 0, 0, 0);
        acc[g][p] = __builtin_amdgcn_mfma_i32_16x16x64_i8(af1, w[g][p][1], acc[g][p], 0, 0, 0);
        acc[g][p] = __builtin_amdgcn_mfma_i32_16x16x64_i8(af2, w[g][p][2], acc[g][p], 0, 0, 0);
        acc[g][p] = __builtin_amdgcn_mfma_i32_16x16x64_i8(af3, w[g][p][3], acc[g][p], 0, 0, 0);
      }

    // gates: native placement (C reg 0), p-half via cndmask
    float z[4];
#pragma unroll
    for (int g = 0; g < 4; ++g) {
      const int zint = (ph == 0) ? acc[g][0][0] : acc[g][1][0];
      z[g] = fmaf((float)zint, dqv[g], bf2f(xc[g]));
    }
    const float zi_ = fminf(fmaxf(z[0], -20.f), 20.f);
    const float zf_ = fminf(fmaxf(z[1], -20.f), 20.f);
    const float zg_ = fminf(fmaxf(z[2], -20.f), 20.f);
    const float zo_ = fminf(fmaxf(z[3], -20.f), 20.f);
    const float ei = fexp2(zi_ * LOG2E);
    const float e2g = fexp2(zg_ * (2.f * LOG2E));
    const float p1 = ei * (e2g - 1.f) * frcp((ei + 1.f) * (e2g + 1.f));
    const float ef = fexp2(-zf_ * LOG2E);
    const float cn = frcp(1.f + ef) * c + p1;
    c = cn;
    const float cc = fminf(fmaxf(cn, -15.f), 15.f);
    const float eo = fexp2(zo_ * LOG2E);
    const float e2c = fexp2(cc * (2.f * LOG2E));
    const float h = eo * (e2c - 1.f) * frcp((eo + 1.f) * (e2c + 1.f));

    // h -> i8, duplicated A-rows in the other buffer
    float hq = rintf(h * 127.f);
    hq = fminf(fmaxf(hq, -127.f), 127.f);
    const signed char hb = (signed char)(int)hq;
    const int woff = curoff ^ 4096;
    As[woff + aw0] = hb;
    As[woff + aw1] = hb;

    *po = h;
    po += 256;
    if (t == lenm) {
      *pc = cn;
      *phl = h;
    }

    xc = xn;
    __syncthreads();
    curoff ^= 4096;
  }
}

// ---------------------------------------------------------------------------
extern "C" void kernel_launch(void* const* d_in, const int* in_sizes, int n_in,
                              void* d_out, int out_size, void* d_ws, size_t ws_size,
                              hipStream_t stream) {
  (void)in_sizes; (void)n_in; (void)out_size; (void)ws_size;
  const float* x = (const float*)d_in[0];
  const float* wi = (const float*)d_in[1];
  const float* wh = (const float*)d_in[2];
  const float* bias = (const float*)d_in[3];
  const int* lens = (const int*)d_in[4];
  float* out = (float*)d_out;

  char* ws = (char*)d_ws;
  unsigned short* xd = (unsigned short*)ws;                         // 64 MiB
  unsigned short* xp = (unsigned short*)(ws + 67108864ull);         // 256 MiB
  unsigned short* wit = (unsigned short*)(ws + 335544320ull);       // 512 KiB
  float* dq = (float*)(ws + 336068608ull);                          // 4 KiB
  float* qs = (float*)(ws + 336072704ull);                          // 4 KiB
  signed char* wqb = (signed char*)(ws + 336076800ull);             // 256 KiB

  k_pack_wi<<<1024, 256, 0, stream>>>(wi, wit);
  k_colscale<<<4, 256, 0, stream>>>(wh, dq, qs);
  k_pack_wh_i8<<<1024, 256, 0, stream>>>(wh, qs, wqb);
  k_dropout<<<32768, 256, 0, stream>>>(x, xd);
  k_gemm_x<<<dim3(1024, 8), 256, 0, stream>>>(xd, wit, bias, xp);
  k_lstm<<<32, 512, 0, stream>>>(xp, wqb, dq, lens, out);
}

// Round 7
// 1541.504 us; speedup vs baseline: 1.3963x; 1.0645x over previous
//
#include <hip/hip_runtime.h>

// ============================================================================
// UnidirecLSTMLayerWithDropoutBefore: dropout(Threefry) -> x@Wi GEMM -> LSTM
// B=64, T=2048, D=256, H=256, gates (i,f,g,o), dropout 0.1, key 42.
//
// R6: k_lstm VALU diet. 2-step unroll (compile-time LDS dbuf parity, zero
// per-step addr math), pre-scaled gates (Xp and dq carry log2e factors;
// z' = fma(cvt(acc),dq',x) -> exp2 direct), upper-only clamps (i,g,o,c),
// magic-number h->i8 quant, cndmask finals. Parallel k_colscale + LDS-
// transpose k_pack_wi. Geometry = R2/R5 (512thr/8waves/32WGx2rows, 1 us4
// Xp read/lane/step). MFMA/SIMD invariant 64/step; target is the VALU tail.
//
// ws layout (bytes):
//   [0, 64MiB)            Xd   bf16 [131072][256]
//   [64MiB, 320MiB)       Xp   bf16 [t*64+b][u*4+g], PRE-SCALED by gate:
//                              i,o: *L   f: *-L   g: *2L   (L = log2e)
//   [335544320, +512KiB)  WiT  bf16 [1024][256]
//   [336068608, +4KiB)    dq   f32 [1024]  (s/127^2 * gate-scale)
//   [336072704, +4KiB)    qs   f32 [1024]  (127/s)
//   [336076800, +256KiB)  Wq   i8 packed MFMA-B frags [ntg][kt][lane][16]
// Output f32: c_last[16384] | h_last[16384] | outputs[64*2048*256]
// ============================================================================

typedef __attribute__((ext_vector_type(8))) short short8;
typedef __attribute__((ext_vector_type(4))) float floatx4;
typedef __attribute__((ext_vector_type(4))) int int4v;
typedef __attribute__((ext_vector_type(4))) unsigned short us4;

#define LOG2E 1.44269504088896f

__device__ __forceinline__ unsigned short f2bf(float f) {
  unsigned int u = __float_as_uint(f);
  u = u + 0x7fffu + ((u >> 16) & 1u);   // RNE
  return (unsigned short)(u >> 16);
}
__device__ __forceinline__ float fexp2(float x) { return __builtin_amdgcn_exp2f(x); }
__device__ __forceinline__ float frcp(float x) { return __builtin_amdgcn_rcpf(x); }

// ---------------------------------------------------------------------------
// Threefry-2x32, key (0,42), partitionable scheme (verified bit-exact R0-R5)
// ---------------------------------------------------------------------------
__device__ __forceinline__ unsigned int tf_bits(unsigned int x0, unsigned int x1) {
  const unsigned int K0 = 0u, K1 = 42u;
  const unsigned int KX = K0 ^ K1 ^ 0x1BD11BDAu;
  x0 += K0; x1 += K1;
#define TF_R(r) { x0 += x1; x1 = (x1 << (r)) | (x1 >> (32 - (r))); x1 ^= x0; }
  TF_R(13) TF_R(15) TF_R(26) TF_R(6)   x0 += K1; x1 += KX + 1u;
  TF_R(17) TF_R(29) TF_R(16) TF_R(24)  x0 += KX; x1 += K0 + 2u;
  TF_R(13) TF_R(15) TF_R(26) TF_R(6)   x0 += K0; x1 += K1 + 3u;
  TF_R(17) TF_R(29) TF_R(16) TF_R(24)  x0 += K1; x1 += KX + 4u;
  TF_R(13) TF_R(15) TF_R(26) TF_R(6)   x0 += KX; x1 += K0 + 5u;
#undef TF_R
  return x0 ^ x1;
}

__global__ __launch_bounds__(256) void k_dropout(const float* __restrict__ x,
                                                 unsigned short* __restrict__ xd) {
  const unsigned int base = (blockIdx.x * 256u + threadIdx.x) * 4u;
  const float4 xv = *reinterpret_cast<const float4*>(x + base);
  const float xs[4] = {xv.x, xv.y, xv.z, xv.w};
  us4 o;
#pragma unroll
  for (int j = 0; j < 4; ++j) {
    const unsigned int bits = tf_bits(0u, base + (unsigned int)j);
    const float u = __uint_as_float((bits >> 9) | 0x3f800000u) - 1.0f;
    const float v = (u < 0.9f) ? (xs[j] / 0.9f) : 0.0f;
    o[j] = f2bf(v);
  }
  *reinterpret_cast<us4*>(xd + base) = o;
}

// LDS-transpose pack: wit[n][k] = bf16(wi[k][n]); coalesced both sides.
__global__ __launch_bounds__(256) void k_pack_wi(const float* __restrict__ wi,
                                                 unsigned short* __restrict__ wit) {
  __shared__ float tile[32][33];
  const int k0 = blockIdx.x * 32, n0 = blockIdx.y * 32;
  const int tx = threadIdx.x & 31, ty = threadIdx.x >> 5;  // 8 rows/pass
#pragma unroll
  for (int i = 0; i < 4; ++i)
    tile[ty + i * 8][tx] = wi[(k0 + ty + i * 8) * 1024 + n0 + tx];
  __syncthreads();
#pragma unroll
  for (int i = 0; i < 4; ++i)
    wit[(n0 + ty + i * 8) * 256 + k0 + tx] = f2bf(tile[tx][ty + i * 8]);
}

// Parallel per-column |max| -> dq (with gate log2e scale baked) and qs.
__global__ __launch_bounds__(256) void k_colscale(const float* __restrict__ wh,
                                                  float* __restrict__ dq,
                                                  float* __restrict__ qs) {
  __shared__ float red[256];
  const int t = threadIdx.x;
  const int n = blockIdx.x * 16 + (t & 15);  // 64 blocks x 16 cols
  const int kg = t >> 4;                     // 16 k-groups x 16 k
  float m = 0.f;
#pragma unroll
  for (int i = 0; i < 16; ++i)
    m = fmaxf(m, fabsf(wh[(kg * 16 + i) * 1024 + n]));
  red[t] = m;
  __syncthreads();
  if (t < 16) {
    const int nn = blockIdx.x * 16 + t;
    float mm = red[t];
#pragma unroll
    for (int j = 1; j < 16; ++j) mm = fmaxf(mm, red[t + j * 16]);
    const float s = (mm > 0.f) ? mm : 1.f;
    const float gsc[4] = {LOG2E, -LOG2E, 2.f * LOG2E, LOG2E};
    dq[nn] = (s / 16129.0f) * gsc[nn >> 8];
    qs[nn] = 127.0f / s;
  }
}

// Wq packed in i8 MFMA-B fragment order (16x16x64) — layout validated R1-R5.
__global__ __launch_bounds__(256) void k_pack_wh_i8(const float* __restrict__ wh,
                                                    const float* __restrict__ qs,
                                                    signed char* __restrict__ wq) {
  const int tid = blockIdx.x * 256 + threadIdx.x;  // 0..262143
  const int j = tid & 15, l = (tid >> 4) & 63, kt = (tid >> 10) & 3, ntg = tid >> 12;
  const int k = kt * 64 + ((l >> 4) << 4) + j;
  const int n = ntg * 16 + (l & 15);
  float v = rintf(wh[k * 1024 + n] * qs[n]);
  v = fminf(fmaxf(v, -127.f), 127.f);
  wq[tid] = (signed char)(int)v;
}

// ---------------------------------------------------------------------------
// K2: Xp[t*64+b][u*4+g] = bf16((Xd @ Wi + b) * gate_scale).
// Block = 128 rows x (32 units x 4 gates); epilogue restaged via LDS.
// ---------------------------------------------------------------------------
__global__ __launch_bounds__(256) void k_gemm_x(const unsigned short* __restrict__ xd,
                                                const unsigned short* __restrict__ wit,
                                                const float* __restrict__ bias,
                                                unsigned short* __restrict__ xp) {
  __shared__ unsigned short SH[20480];
  const int tid = threadIdx.x;
  const int lane = tid & 63;
  const int wv = tid >> 6;
  const int wm = wv >> 1, wn = wv & 1;
  const int m0 = blockIdx.x * 128;
  const int y = blockIdx.y;

  const int srow = tid >> 1, sseg = tid & 1;
  const unsigned short* gA = xd + (m0 + srow) * 256 + sseg * 16;
  const int nsrc = ((srow >> 5) << 8) + y * 32 + (srow & 31);
  const unsigned short* gB = wit + nsrc * 256 + sseg * 16;
  const int soff = srow * 40 + sseg * 16;

  const floatx4 zero4 = {0.f, 0.f, 0.f, 0.f};
  floatx4 acc[4][4];
#pragma unroll
  for (int i = 0; i < 4; ++i)
#pragma unroll
    for (int j = 0; j < 4; ++j) acc[i][j] = zero4;

  short8 ra0 = *(const short8*)(gA);
  short8 ra1 = *(const short8*)(gA + 8);
  short8 rb0 = *(const short8*)(gB);
  short8 rb1 = *(const short8*)(gB + 8);
  *(short8*)&SH[soff] = ra0;
  *(short8*)&SH[soff + 8] = ra1;
  *(short8*)&SH[10240 + soff] = rb0;
  *(short8*)&SH[10240 + soff + 8] = rb1;
  __syncthreads();

  const int frow = (lane & 15) * 40 + ((lane >> 4) << 3);
#pragma unroll 1
  for (int kt = 0; kt < 8; ++kt) {
    const int boff = (kt & 1) * 5120;
    if (kt < 7) {
      ra0 = *(const short8*)(gA + (kt + 1) * 32);
      ra1 = *(const short8*)(gA + (kt + 1) * 32 + 8);
      rb0 = *(const short8*)(gB + (kt + 1) * 32);
      rb1 = *(const short8*)(gB + (kt + 1) * 32 + 8);
    }
    short8 af[4], bfv[4];
#pragma unroll
    for (int mt = 0; mt < 4; ++mt)
      af[mt] = *(const short8*)&SH[boff + (wm * 64 + mt * 16) * 40 + frow];
#pragma unroll
    for (int nt = 0; nt < 4; ++nt)
      bfv[nt] = *(const short8*)&SH[10240 + boff + (wn * 64 + nt * 16) * 40 + frow];
#pragma unroll
    for (int mt = 0; mt < 4; ++mt)
#pragma unroll
      for (int nt = 0; nt < 4; ++nt)
        acc[mt][nt] = __builtin_amdgcn_mfma_f32_16x16x32_bf16(af[mt], bfv[nt], acc[mt][nt], 0, 0, 0);
    if (kt < 7) {
      const int noff = (boff ^ 5120);
      *(short8*)&SH[noff + soff] = ra0;
      *(short8*)&SH[noff + soff + 8] = ra1;
      *(short8*)&SH[10240 + noff + soff] = rb0;
      *(short8*)&SH[10240 + noff + soff + 8] = rb1;
    }
    __syncthreads();
  }

  // bias + gate scale per nt: gate = wn*2 + (nt>>1)
  const float gsc[4] = {LOG2E, -LOG2E, 2.f * LOG2E, LOG2E};
  float bv[4], gv[4];
#pragma unroll
  for (int nt = 0; nt < 4; ++nt) {
    const int gate = wn * 2 + (nt >> 1);
    bv[nt] = bias[(gate << 8) + y * 32 + ((nt & 1) << 4) + (lane & 15)];
    gv[nt] = gsc[gate];
  }

  __syncthreads();
#pragma unroll
  for (int mt = 0; mt < 4; ++mt) {
#pragma unroll
    for (int nt = 0; nt < 4; ++nt) {
      const int jj = wn * 64 + nt * 16 + (lane & 15);
#pragma unroll
      for (int q = 0; q < 4; ++q) {
        const int row = wm * 64 + mt * 16 + ((lane >> 4) << 2) + q;
        SH[row * 132 + jj] = f2bf((acc[mt][nt][q] + bv[nt]) * gv[nt]);
      }
    }
  }
  __syncthreads();

#pragma unroll
  for (int k = 0; k < 16; ++k) {
    const int pi = k * 256 + tid;
    const int row = pi >> 5, u = pi & 31;
    us4 o = {SH[row * 132 + u], SH[row * 132 + 32 + u],
             SH[row * 132 + 64 + u], SH[row * 132 + 96 + u]};
    const int m = m0 + row;
    *(us4*)(xp + ((size_t)(m & 2047) * 64 + (m >> 11)) * 1024 +
            (size_t)(y * 32 + u) * 4) = o;
  }
}

// ---------------------------------------------------------------------------
// K3: weight-resident LSTM scan. 32 WGs x 2 rows, 512 thr (8 waves, 2/SIMD).
// 2-step unrolled: even t reads buf0/writes buf1, odd the reverse — all LDS
// addressing via one base reg + compile-time offsets. Gates pre-scaled.
// ---------------------------------------------------------------------------
__global__ __launch_bounds__(512, 2) void k_lstm(const unsigned short* __restrict__ xp,
                                                 const signed char* __restrict__ wq,
                                                 const float* __restrict__ dq,
                                                 const int* __restrict__ lens,
                                                 float* __restrict__ out) {
  __shared__ __align__(16) signed char As[8192];  // 2 x [kt<4][alane<64][16] i8

  const int tid = threadIdx.x, lane = tid & 63, v = tid >> 6;
  const int wg = blockIdx.x, b0 = wg * 2;

  const int4v zacc = {0, 0, 0, 0};
  ((int4v*)As)[tid] = zacc;

  // resident weights: 32 frags/lane
  int4v w[4][2][4];
#pragma unroll
  for (int g = 0; g < 4; ++g)
#pragma unroll
    for (int p = 0; p < 2; ++p)
#pragma unroll
      for (int kt = 0; kt < 4; ++kt) {
        const int ntg = g * 16 + v * 2 + p;
        w[g][p][kt] = *(const int4v*)(wq + (size_t)(((ntg * 4 + kt) * 64 + lane)) * 16);
      }

  const int r = (lane >> 4) & 1;
  const int ph = lane >> 5;
  const int u = v * 32 + ph * 16 + (lane & 15);

  float dq0 = dq[u], dq1 = dq[256 + u], dq2 = dq[512 + u], dq3 = dq[768 + u];
  const int lenm = lens[b0 + r] - 1;
  float c = 0.f, ckeep = 0.f, hkeep = 0.f;

  // LDS bases: reads at AsR + {0..3072} (buf0) / {4096..7168} (buf1);
  // writes at AsW + {4096,4224} (even) / {0,128} (odd).
  const signed char* AsR = As + lane * 16;
  signed char* AsW = As + ((u >> 6) * 1024 + (((u >> 4) & 3) * 16 + r * 4) * 16 + (u & 15));

  // global offsets (32-bit, byte): Xp us4 and out f32
  const char* xpb = (const char*)xp;
  unsigned int xoff = ((unsigned int)(b0 + r) * 1024u + (unsigned int)u * 4u) * 2u;
  char* outb = (char*)(out + 32768);
  unsigned int ooff = ((unsigned int)(b0 + r) * 524288u + (unsigned int)u) * 4u;

  uint2 xc = *(const uint2*)(xpb + xoff);
  xoff += 131072u;

  __syncthreads();

#define GATES(XPAIR, WOFF0, WOFF1)                                              \
  {                                                                             \
    const float xi = __uint_as_float(XPAIR.x << 16);                            \
    const float xf = __uint_as_float(XPAIR.x & 0xffff0000u);                    \
    const float xg = __uint_as_float(XPAIR.y << 16);                            \
    const float xo = __uint_as_float(XPAIR.y & 0xffff0000u);                    \
    const int ai = ph ? acc[0][1][0] : acc[0][0][0];                            \
    const int af_ = ph ? acc[1][1][0] : acc[1][0][0];                           \
    const int ag = ph ? acc[2][1][0] : acc[2][0][0];                            \
    const int ao = ph ? acc[3][1][0] : acc[3][0][0];                            \
    const float zi = fminf(fmaf((float)ai, dq0, xi), 28.85f);                   \
    const float zf = fmaf((float)af_, dq1, xf);                                 \
    const float zg = fminf(fmaf((float)ag, dq2, xg), 57.71f);                   \
    const float zo = fminf(fmaf((float)ao, dq3, xo), 28.85f);                   \
    const float ei = fexp2(zi);                                                 \
    const float e2g = fexp2(zg);                                                \
    const float ef = fexp2(zf);                                                 \
    const float eo = fexp2(zo);                                                 \
    const float p1 = ei * (e2g - 1.f) * frcp((ei + 1.f) * (e2g + 1.f));         \
    const float cn = fmaf(frcp(1.f + ef), c, p1);                               \
    c = cn;                                                                     \
    const float e2c = fexp2(fminf(cn, 15.f) * (2.f * LOG2E));                   \
    const float h = eo * (e2c - 1.f) * frcp((eo + 1.f) * (e2c + 1.f));          \
    const float hm = fmaf(h, 127.f, 12582912.f);                                \
    AsW[WOFF0] = (signed char)__float_as_uint(hm);                              \
    AsW[WOFF1] = (signed char)__float_as_uint(hm);                              \
    *(float*)(outb + ooff) = h;                                                 \
    ooff += 1024u;                                                              \
    if (t_ == lenm) { ckeep = cn; hkeep = h; }                                  \
  }

#define MFMA_BLOCK(O0, O1, O2, O3)                                              \
  int4v acc[4][2];                                                              \
  {                                                                             \
    const int4v a0 = *(const int4v*)(AsR + (O0));                               \
    const int4v a1 = *(const int4v*)(AsR + (O1));                               \
    const int4v a2 = *(const int4v*)(AsR + (O2));                               \
    const int4v a3 = *(const int4v*)(AsR + (O3));                               \
    _Pragma("unroll") for (int g = 0; g < 4; ++g)                               \
    _Pragma("unroll") for (int p = 0; p < 2; ++p) {                             \
      acc[g][p] = __builtin_amdgcn_mfma_i32_16x16x64_i8(a0, w[g][p][0], zacc, 0, 0, 0); \
      acc[g][p] = __builtin_amdgcn_mfma_i32_16x16x64_i8(a1, w[g][p][1], acc[g][p], 0, 0, 0); \
      acc[g][p] = __builtin_amdgcn_mfma_i32_16x16x64_i8(a2, w[g][p][2], acc[g][p], 0, 0, 0); \
      acc[g][p] = __builtin_amdgcn_mfma_i32_16x16x64_i8(a3, w[g][p][3], acc[g][p], 0, 0, 0); \
    }                                                                           \
  }

#pragma unroll 1
  for (int it = 0; it < 1024; ++it) {
    {  // even t = 2*it: read buf0, write buf1
      const int t_ = 2 * it;
      const uint2 xn = *(const uint2*)(xpb + xoff);  // prefetch for odd half
      xoff += 131072u;
      MFMA_BLOCK(0, 1024, 2048, 3072)
      GATES(xc, 4096, 4224)
      xc = xn;  // dead after odd half consumes; renamed by compiler
      __syncthreads();
    }
    {  // odd t = 2*it+1: read buf1, write buf0
      const int t_ = 2 * it + 1;
      const uint2 xn = *(const uint2*)(xpb + xoff);  // prefetch for next even
      xoff += 131072u;
      MFMA_BLOCK(4096, 5120, 6144, 7168)
      GATES(xc, 0, 128)
      xc = xn;
      __syncthreads();
    }
  }
#undef GATES
#undef MFMA_BLOCK

  out[(size_t)(b0 + r) * 256 + u] = ckeep;
  out[16384 + (size_t)(b0 + r) * 256 + u] = hkeep;
}

// ---------------------------------------------------------------------------
extern "C" void kernel_launch(void* const* d_in, const int* in_sizes, int n_in,
                              void* d_out, int out_size, void* d_ws, size_t ws_size,
                              hipStream_t stream) {
  (void)in_sizes; (void)n_in; (void)out_size; (void)ws_size;
  const float* x = (const float*)d_in[0];
  const float* wi = (const float*)d_in[1];
  const float* wh = (const float*)d_in[2];
  const float* bias = (const float*)d_in[3];
  const int* lens = (const int*)d_in[4];
  float* out = (float*)d_out;

  char* ws = (char*)d_ws;
  unsigned short* xd = (unsigned short*)ws;                         // 64 MiB
  unsigned short* xp = (unsigned short*)(ws + 67108864ull);         // 256 MiB
  unsigned short* wit = (unsigned short*)(ws + 335544320ull);       // 512 KiB
  float* dq = (float*)(ws + 336068608ull);                          // 4 KiB
  float* qs = (float*)(ws + 336072704ull);                          // 4 KiB
  signed char* wqb = (signed char*)(ws + 336076800ull);             // 256 KiB

  k_pack_wi<<<dim3(8, 32), 256, 0, stream>>>(wi, wit);
  k_colscale<<<64, 256, 0, stream>>>(wh, dq, qs);
  k_pack_wh_i8<<<1024, 256, 0, stream>>>(wh, qs, wqb);
  k_dropout<<<32768, 256, 0, stream>>>(x, xd);
  k_gemm_x<<<dim3(1024, 8), 256, 0, stream>>>(xd, wit, bias, xp);
  k_lstm<<<32, 512, 0, stream>>>(xp, wqb, dq, lens, out);
}